// Round 3
// baseline (79.694 us; speedup 1.0000x reference)
//
#include <hip/hip_runtime.h>

// Problem constants: B=4, K=8, H=W=64 -> N=4096, D=64, codes are 8-bit.
#define BATCH  4
#define KBITS  8
#define NPOS   4096
#define DDIM   64
#define NCODES 256
#define HPART  4   // partial histograms per batch

// ---------------------------------------------------------------------------
// K1: 4 blocks per batch (grid=16), 256 threads, 4 positions/thread.
// Compute 8-bit codes from z>0.5, write codes, private LDS histogram of
// evidence codes -> hist_part[block][256]. No global atomics, no memset.
// ---------------------------------------------------------------------------
__global__ void k_codes_hist(const float* __restrict__ z,
                             const int* __restrict__ evidence_mask,
                             unsigned char* __restrict__ codes,
                             int* __restrict__ hist_part) {
    const int b   = blockIdx.x >> 2;
    const int q   = blockIdx.x & 3;
    const int tid = threadIdx.x;

    __shared__ int h[NCODES];
    h[tid] = 0;
    __syncthreads();

    const float* zb = z + (size_t)b * KBITS * NPOS;
    const int nbase = q * 1024;
#pragma unroll
    for (int i = 0; i < 4; ++i) {
        const int n = nbase + i * 256 + tid;
        int code = 0;
#pragma unroll
        for (int k = 0; k < KBITS; ++k) {
            code |= (int)(zb[k * NPOS + n] > 0.5f) << k;
        }
        codes[b * NPOS + n] = (unsigned char)code;
        if (evidence_mask[b * NPOS + n] != 0) {
            atomicAdd(&h[code], 1);  // LDS atomic
        }
    }
    __syncthreads();
    hist_part[blockIdx.x * NCODES + tid] = h[tid];
}

// ---------------------------------------------------------------------------
// K2: one WAVE per (batch, query-code): grid=1024, 64 threads.
// rowg[b][cq][d] = sum_c cnt[c]*exp((mn - pop(cq^c))/t)*VT[c][d] / denom
// cnt summed from 4 partial hists. Predicated weight avoids 0*inf=NaN.
// All-masked batch -> all cnt==0 -> weights 0 -> den 0 -> output 0 (= ref).
// ---------------------------------------------------------------------------
__global__ void k_table(const int* __restrict__ hist_part,
                        const float* __restrict__ value_table,
                        const float* __restrict__ temperature,
                        float* __restrict__ rowg) {
    const int b  = blockIdx.x >> 8;
    const int cq = blockIdx.x & 255;
    const int d  = threadIdx.x;  // 0..63, one wave

    __shared__ float wrow[NCODES];

    int cnt[4], pop[4];
    int myMn = 99;
#pragma unroll
    for (int j = 0; j < 4; ++j) {
        const int c = j * 64 + d;
        int s = 0;
#pragma unroll
        for (int q = 0; q < HPART; ++q) {
            s += hist_part[(b * HPART + q) * NCODES + c];  // coalesced in d
        }
        cnt[j] = s;
        pop[j] = __popc(cq ^ c);
        if (s > 0) myMn = min(myMn, pop[j]);
    }
#pragma unroll
    for (int off = 32; off > 0; off >>= 1) myMn = min(myMn, __shfl_down(myMn, off));
    const int mn = __shfl(myMn, 0);

    const float inv_t = 1.0f / fmaxf(temperature[0], 0.1f);
#pragma unroll
    for (int j = 0; j < 4; ++j) {
        wrow[j * 64 + d] = (cnt[j] > 0)
            ? (float)cnt[j] * __expf((float)(mn - pop[j]) * inv_t)
            : 0.0f;
    }
    __syncthreads();

    float acc = 0.0f, den = 0.0f;
#pragma unroll 16
    for (int c4 = 0; c4 < 64; ++c4) {
        const float4 w = *(const float4*)&wrow[c4 * 4];  // uniform: broadcast
        const float* vp = value_table + c4 * 4 * DDIM + d;
        den += (w.x + w.y) + (w.z + w.w);
        acc = fmaf(w.x, vp[0],        acc);
        acc = fmaf(w.y, vp[DDIM],     acc);
        acc = fmaf(w.z, vp[2 * DDIM], acc);
        acc = fmaf(w.w, vp[3 * DDIM], acc);
    }
    rowg[blockIdx.x * DDIM + d] = acc / fmaxf(den, 1e-20f);
}

// ---------------------------------------------------------------------------
// K3: gather. out (B, D, N): out[(b*D+d)*N + n] = rowg[b][codes[b][n]][d]
// 8 elements/thread: two uchar4 code loads, two float4 stores. grid=512.
// ---------------------------------------------------------------------------
__global__ void k_gather(const unsigned char* __restrict__ codes,
                         const float* __restrict__ rowg,
                         float* __restrict__ out) {
    const int gid  = blockIdx.x * 256 + threadIdx.x;   // < 131072
    const int base = gid * 8;                          // element index
    const int n8   = base & (NPOS - 1);
    const int bd   = base >> 12;
    const int d    = bd & (DDIM - 1);
    const int b    = bd >> 6;

    const uchar4* cp = (const uchar4*)(codes + b * NPOS + n8);
    const uchar4 c0 = cp[0], c1 = cp[1];
    const float* rb = rowg + (b << 14) + d;  // b*256*64 + d
    float4 o0, o1;
    o0.x = rb[(int)c0.x << 6];
    o0.y = rb[(int)c0.y << 6];
    o0.z = rb[(int)c0.z << 6];
    o0.w = rb[(int)c0.w << 6];
    o1.x = rb[(int)c1.x << 6];
    o1.y = rb[(int)c1.y << 6];
    o1.z = rb[(int)c1.z << 6];
    o1.w = rb[(int)c1.w << 6];
    float4* op = (float4*)(out + base);
    op[0] = o0;
    op[1] = o1;
}

extern "C" void kernel_launch(void* const* d_in, const int* in_sizes, int n_in,
                              void* d_out, int out_size, void* d_ws, size_t ws_size,
                              hipStream_t stream) {
    const float* z            = (const float*)d_in[0];  // (B,K,H,W) fp32
    const int*   evidence     = (const int*)d_in[1];    // (B,N) bool->int32
    const float* temperature  = (const float*)d_in[2];  // scalar
    const float* value_table  = (const float*)d_in[3];  // (256,D) fp32
    // d_in[4] mask_value: never contributes (attn==0 off-evidence)
    // d_in[5] pop_lut: replaced by __popc

    float* out = (float*)d_out;  // (B,D,H,W) fp32

    unsigned char* codes     = (unsigned char*)d_ws;            // 16384 B
    int*           hist_part = (int*)((char*)d_ws + 16384);     // 16 KiB
    float*         rowg      = (float*)((char*)d_ws + 32768);   // 256 KiB

    k_codes_hist<<<BATCH * HPART, 256, 0, stream>>>(z, evidence, codes, hist_part);
    k_table<<<BATCH * NCODES, 64, 0, stream>>>(hist_part, value_table, temperature, rowg);
    k_gather<<<(BATCH * DDIM * NPOS) / (256 * 8), 256, 0, stream>>>(codes, rowg, out);
}